// Round 13
// baseline (280.779 us; speedup 1.0000x reference)
//
#include <hip/hip_runtime.h>
#include <hip/hip_bf16.h>
#include <cstdint>

#define B_  2
#define C_  128
#define HH  128
#define WW  128
#define L_  4096
#define K1  1152
#define M2  2048
#define NPAD 3072
#define NCAND 16
#define MARGIN 0.15f
#define PCUT 1e-3f
#define MAXC 512

typedef __attribute__((ext_vector_type(8))) short bf16x8s;
typedef __attribute__((ext_vector_type(4))) float f32x4;
typedef __attribute__((ext_vector_type(2))) float f32x2;
using bf16 = __hip_bfloat16;

__device__ inline float bf16bits2f(unsigned short s) {
  uint32_t u = ((uint32_t)s) << 16;
  return __builtin_bit_cast(float, u);
}
__device__ inline unsigned short f2bf16bits(float x) {  // RTNE
  uint32_t u = __builtin_bit_cast(uint32_t, x);
  u += 0x7fffu + ((u >> 16) & 1u);
  return (unsigned short)(u >> 16);
}

// OCP e4m3 encode (RTNE)
__device__ inline uint8_t fp8_encode(float v) {
  uint32_t s = (__builtin_bit_cast(uint32_t, v) >> 24) & 0x80u;
  float av = fabsf(v);
  uint32_t byte;
  if (av >= 0.015625f) {
    uint32_t bits = __builtin_bit_cast(uint32_t, av);
    uint32_t mant = bits & 0x7fffffu;
    uint32_t E = bits >> 23;
    uint32_t m3 = (mant + 0x7ffffu + ((mant >> 20) & 1u)) >> 20;
    if (m3 == 8u) { m3 = 0u; E++; }
    int e8 = (int)E - 120;
    if (e8 > 15) { e8 = 15; m3 = 6; }
    byte = ((uint32_t)e8 << 3) | m3;
  } else {
    byte = (uint32_t)(av * 512.f + 0.5f);
  }
  return (uint8_t)(s | byte);
}

#if __has_builtin(__builtin_amdgcn_cvt_pk_f32_fp8)
#define FP8PK(d, hi) __builtin_amdgcn_cvt_pk_f32_fp8((d), (hi))
#else
__device__ inline f32x2 FP8PK(uint32_t d, bool hi) {
  uint32_t b0 = hi ? ((d >> 16) & 0xffu) : (d & 0xffu);
  uint32_t b1 = hi ? (d >> 24) : ((d >> 8) & 0xffu);
  f32x2 r;
  r.x = __builtin_bit_cast(float, ((b0 & 0x80u) << 24) | ((b0 & 0x7fu) << 20)) * 0x1p120f;
  r.y = __builtin_bit_cast(float, ((b1 & 0x80u) << 24) | ((b1 & 0x7fu) << 20)) * 0x1p120f;
  return r;
}
#endif

__device__ inline void gload_lds16(const void* g, void* l) {
  auto gp = reinterpret_cast<const __attribute__((address_space(1))) uint32_t*>(
      reinterpret_cast<uintptr_t>(g));
  auto lp = reinterpret_cast<__attribute__((address_space(3))) uint32_t*>(
      reinterpret_cast<uintptr_t>(l));
  __builtin_amdgcn_global_load_lds(gp, lp, 16, 0, 0);
}

// ---------------- mask validity + valid-column compaction (single block)
__global__ __launch_bounds__(256) void compact_k(const float* __restrict__ mask,
                                                 float* __restrict__ mm,
                                                 int* __restrict__ vlist,
                                                 int* __restrict__ vmap,
                                                 int* __restrict__ meta) {
  __shared__ int wpart[4];
  int t = threadIdx.x;
  int lane = t & 63, wid = t >> 6;
  int loc[16];
  float mmv[16];
  int cnt = 0;
#pragma unroll
  for (int s = 0; s < 16; ++s) {
    int l = t * 16 + s;
    int i = l >> 6, j = l & 63;
    float sum = 0.f;
    for (int p = -1; p <= 1; ++p)
      for (int q = -1; q <= 1; ++q) {
        int y = i + p, x = j + q;
        if ((unsigned)y < 64u && (unsigned)x < 64u)
          sum += mask[(size_t)(8 * y) * 512 + 8 * x];
      }
    mmv[s] = (sum == 0.f) ? 1.f : 0.f;
    mm[l] = mmv[s];
    loc[s] = cnt;
    cnt += (mmv[s] != 0.f) ? 1 : 0;
  }
  int pre = cnt;
#pragma unroll
  for (int o = 1; o < 64; o <<= 1) {
    int u = __shfl_up(pre, o);
    if (lane >= o) pre += u;
  }
  if (lane == 63) wpart[wid] = pre;
  int excl = pre - cnt;
  __syncthreads();
  int base = 0;
  for (int w = 0; w < wid; ++w) base += wpart[w];
  int mybase = base + excl;
#pragma unroll
  for (int s = 0; s < 16; ++s) {
    int l = t * 16 + s;
    if (mmv[s] != 0.f) {
      int pos = mybase + loc[s];
      vlist[pos] = l;
      vmap[l] = pos;
    }
  }
  if (t == 0) {
    int total = wpart[0] + wpart[1] + wpart[2] + wpart[3];
    meta[0] = total;
    meta[1] = L_ - total;
  }
}

// ---------------- fused prep: [0,8192) prep_u | [8192,45056) prep_fp | rest prep_bmat
#define PU_BLKS (B_ * L_)                       // 8192
#define PF_BLKS (B_ * L_ * K1 / 256)            // 36864
#define PB_BLKS (B_ * M2 * L_ / 256)            // 65536
__global__ __launch_bounds__(256) void prep_all_k(const float* __restrict__ f,
                                                  const float* __restrict__ b,
                                                  const float* __restrict__ mm,
                                                  const int* __restrict__ vmap,
                                                  bf16* __restrict__ Ucomp,
                                                  float* __restrict__ U32,
                                                  bf16* __restrict__ FP,
                                                  float* __restrict__ FP32,
                                                  uint8_t* __restrict__ BmT8) {
  int bx = blockIdx.x;
  int t = threadIdx.x;
  if (bx < PU_BLKS) {
    // ---- prep_u: block = (l, bi)
    __shared__ float red[4];
    int l = bx & (L_ - 1);
    int bi = bx >> 12;
    if (mm[l] == 0.f) return;
    int pos = vmap[l];
    int i = l >> 6, j = l & 63;
    float vals[5];
    float ss = 0.f;
#pragma unroll
    for (int s = 0; s < 5; ++s) {
      int k = t + s * 256;
      float v = 0.f;
      if (k < K1) {
        int c = k / 9, r = k - c * 9;
        int p = r / 3, q = r - p * 3;
        int y = i + p - 1, x = j + q - 1;
        if ((unsigned)y < 64u && (unsigned)x < 64u)
          v = b[(((size_t)bi * C_ + c) * HH + 2 * y) * WW + 2 * x];
      }
      vals[s] = v;
      ss += v * v;
    }
#pragma unroll
    for (int o = 32; o; o >>= 1) ss += __shfl_xor(ss, o);
    if ((t & 63) == 0) red[t >> 6] = ss;
    __syncthreads();
    float tot = red[0] + red[1] + red[2] + red[3];
    float den = fmaxf(sqrtf(tot), 1e-4f);
    float inv = 1.f / den;
    size_t cbase = ((size_t)bi * NPAD + pos) * K1;
    size_t obase = ((size_t)bi * L_ + l) * K1;
#pragma unroll
    for (int s = 0; s < 5; ++s) {
      int k = t + s * 256;
      if (k < K1) {
        float u = vals[s] * inv;
        Ucomp[cbase + k] = __float2bfloat16(u);
        U32[obase + k] = u;
      }
    }
  } else if (bx < PU_BLKS + PF_BLKS) {
    // ---- prep_fp: flat over B*L*K1
    int gidx = (bx - PU_BLKS) * 256 + t;
    int bi = gidx / (L_ * K1);
    int idx = gidx - bi * (L_ * K1);
    int hw = idx / K1, k = idx - hw * K1;
    int h = hw >> 6, w = hw & 63;
    int c = k / 9, r = k - c * 9;
    int p = r / 3, q = r - p * 3;
    int y = h + p - 1, x = w + q - 1;
    float v = 0.f;
    if ((unsigned)y < 64u && (unsigned)x < 64u)
      v = f[(((size_t)bi * C_ + c) * HH + 2 * y) * WW + 2 * x];
    size_t o = (size_t)gidx;
    FP[o] = __float2bfloat16(v);
    FP32[o] = v;
  } else {
    // ---- prep_bmat: flat over B*M2*L  (M2*L = 2^23)
    int gidx = (bx - PU_BLKS - PF_BLKS) * 256 + t;
    int bi = gidx >> 23;
    int idx = gidx & (M2 * L_ - 1);
    int l = idx >> 11, m = idx & 2047;
    int c = m >> 4, p = (m >> 2) & 3, q = m & 3;
    int i = l >> 6, j = l & 63;
    int y = 2 * i + p - 1, x = 2 * j + q - 1;
    float v = 0.f;
    if ((unsigned)y < 128u && (unsigned)x < 128u)
      v = b[(((size_t)bi * C_ + c) * HH + y) * WW + x];
    BmT8[(size_t)gidx] = fp8_encode(v);
  }
}

// ---------------- GEMM (R9 body): 128x128, BK=32, 2-buffer, global_load_lds,
// + XCD-aware bijective swizzle (1536 = 192*8 blocks, bn-major per XCD).
__global__ __launch_bounds__(256) void gemm_bt(const bf16* __restrict__ A,
                                               const bf16* __restrict__ Bbase,
                                               bf16* __restrict__ C,
                                               int N, int K) {
  __shared__ __align__(16) bf16 sA[2][128][32];
  __shared__ __align__(16) bf16 sB[2][128][32];
  const int wg = blockIdx.x;                   // 0..1535
  const int swz = (wg & 7) * 192 + (wg >> 3);  // bijective (1536 % 8 == 0)
  const int bm = (swz & 63) * 128;             // M tile (64)
  const int bn = (swz >> 6) * 128;             // N tile (24)
  const int tid = threadIdx.x;
  const int lane = tid & 63;
  const int wid = tid >> 6;
  const bf16* B = Bbase + (size_t)(bm >> 12) * NPAD * K1;
  const int wm = (wid >> 1) * 64;
  const int wn = (wid & 1) * 64;
  const int lrow = lane & 15;
  const int lko = (lane >> 4) * 8;

  f32x4 acc[4][4];
#pragma unroll
  for (int i = 0; i < 4; ++i)
#pragma unroll
    for (int j = 0; j < 4; ++j) acc[i][j] = (f32x4){0.f, 0.f, 0.f, 0.f};

  const int nt = K >> 5;
  const int s0 = tid, s1 = tid + 256;
  const int ar0 = s0 >> 2, ac0 = (s0 & 3) * 8;
  const int ar1 = s1 >> 2, ac1 = (s1 & 3) * 8;

  auto STAGE = [&](int bufi, int t) {
    const int k0 = t * 32;
    gload_lds16(A + (size_t)(bm + ar0) * K + k0 + ac0, &sA[bufi][ar0][ac0]);
    gload_lds16(A + (size_t)(bm + ar1) * K + k0 + ac1, &sA[bufi][ar1][ac1]);
    gload_lds16(B + (size_t)(bn + ar0) * K + k0 + ac0, &sB[bufi][ar0][ac0]);
    gload_lds16(B + (size_t)(bn + ar1) * K + k0 + ac1, &sB[bufi][ar1][ac1]);
  };

  STAGE(0, 0);
  __syncthreads();
  int buf = 0;
  for (int t = 0; t < nt; ++t) {
    if (t + 1 < nt) STAGE(buf ^ 1, t + 1);
    bf16x8s af[4], bfr[4];
#pragma unroll
    for (int fm = 0; fm < 4; ++fm)
      af[fm] = *(const bf16x8s*)&sA[buf][wm + fm * 16 + lrow][lko];
#pragma unroll
    for (int fn = 0; fn < 4; ++fn)
      bfr[fn] = *(const bf16x8s*)&sB[buf][wn + fn * 16 + lrow][lko];
#pragma unroll
    for (int fm = 0; fm < 4; ++fm)
#pragma unroll
      for (int fn = 0; fn < 4; ++fn)
        acc[fm][fn] = __builtin_amdgcn_mfma_f32_16x16x32_bf16(af[fm], bfr[fn], acc[fm][fn], 0, 0, 0);
    __syncthreads();
    buf ^= 1;
  }

  const int crow = (lane >> 4) * 4;
  const int ccol = lane & 15;
#pragma unroll
  for (int fm = 0; fm < 4; ++fm)
#pragma unroll
    for (int fn = 0; fn < 4; ++fn) {
      int r0 = bm + wm + fm * 16 + crow;
      int c0 = bn + wn + fn * 16 + ccol;
#pragma unroll
      for (int r = 0; r < 4; ++r)
        C[(size_t)(r0 + r) * N + c0] = __float2bfloat16(acc[fm][fn][r]);
    }
}

// ---------------- fused softmax + sparse PV, batched (blockIdx.y = bi)
__global__ __launch_bounds__(256) void softmax_spmv_k(const bf16* __restrict__ Sb,
                                                      const int* __restrict__ vlist,
                                                      const int* __restrict__ meta,
                                                      const uint8_t* __restrict__ BmT8b,
                                                      unsigned short* __restrict__ Ztb,
                                                      int* __restrict__ candb,
                                                      int* __restrict__ candcntb) {
  __shared__ float rmax[4];
  __shared__ float rsum[4];
  __shared__ int scnt, mcnt;
  __shared__ int slist[MAXC];
  __shared__ float splist[MAXC];
  __shared__ int mlist[NCAND];
  const int row = blockIdx.x;
  const int bi = blockIdx.y;
  const int t = threadIdx.x;
  const int vcnt = meta[0];
  const int nmask = meta[1];
  const uint8_t* BmT8 = BmT8b + (size_t)bi * M2 * L_;
  if (t == 0) { scnt = 0; mcnt = 0; }
  const bool has = (t < NPAD / 16);
  const int c0 = t * 16;
  float xs[16];
#pragma unroll
  for (int s = 0; s < 16; ++s) xs[s] = -1e30f;
  if (has) {
    const bf16* srow = Sb + ((size_t)bi * L_ + row) * NPAD;
    bf16x8s sv0 = *(const bf16x8s*)&srow[c0];
    bf16x8s sv1 = *(const bf16x8s*)&srow[c0 + 8];
#pragma unroll
    for (int s = 0; s < 8; ++s) {
      xs[s] = bf16bits2f((unsigned short)sv0[s]);
      xs[s + 8] = bf16bits2f((unsigned short)sv1[s]);
    }
  }
  float vmax = -1e30f;
#pragma unroll
  for (int s = 0; s < 16; ++s)
    if (has && c0 + s < vcnt) vmax = fmaxf(vmax, xs[s]);
#pragma unroll
  for (int o = 32; o; o >>= 1) vmax = fmaxf(vmax, __shfl_xor(vmax, o));
  if ((t & 63) == 0) rmax[t >> 6] = vmax;
  __syncthreads();
  vmax = fmaxf(fmaxf(rmax[0], rmax[1]), fmaxf(rmax[2], rmax[3]));
  float gmax = (nmask > 0) ? fmaxf(vmax, 0.f) : vmax;
  float zs = 0.f;
#pragma unroll
  for (int s = 0; s < 16; ++s)
    if (has && c0 + s < vcnt) zs += __expf(10.f * (xs[s] - gmax));
#pragma unroll
  for (int o = 32; o; o >>= 1) zs += __shfl_xor(zs, o);
  if ((t & 63) == 0) rsum[t >> 6] = zs;
  __syncthreads();
  zs = rsum[0] + rsum[1] + rsum[2] + rsum[3] + (float)nmask * __expf(-10.f * gmax);
  float invZ = 1.f / zs;
  float cutx = gmax + __logf(PCUT * zs) * 0.1f;
  if (has) {
#pragma unroll
    for (int s = 0; s < 16; ++s) {
      int c = c0 + s;
      if (c < vcnt) {
        if (xs[s] >= cutx) {
          int pos = atomicAdd(&scnt, 1);
          if (pos < MAXC) {
            slist[pos] = vlist[c];
            splist[pos] = __expf(10.f * (xs[s] - gmax)) * invZ;
          }
        }
        if (xs[s] >= vmax - MARGIN) {
          int pos = atomicAdd(&mcnt, 1);
          if (pos < NCAND) mlist[pos] = vlist[c];
        }
      }
    }
  }
  __syncthreads();
  int nc = min(scnt, MAXC);
  float acc[8] = {0.f, 0.f, 0.f, 0.f, 0.f, 0.f, 0.f, 0.f};
#pragma unroll 4
  for (int ci = 0; ci < nc; ++ci) {
    int l = slist[ci];
    float p = splist[ci];
    const uint32_t* bp = (const uint32_t*)(BmT8 + (size_t)l * M2) + t * 2;
    uint32_t d0 = bp[0], d1 = bp[1];
    f32x2 w0 = FP8PK(d0, false);
    f32x2 w1 = FP8PK(d0, true);
    f32x2 w2 = FP8PK(d1, false);
    f32x2 w3 = FP8PK(d1, true);
    acc[0] += p * w0.x; acc[1] += p * w0.y;
    acc[2] += p * w1.x; acc[3] += p * w1.y;
    acc[4] += p * w2.x; acc[5] += p * w2.y;
    acc[6] += p * w3.x; acc[7] += p * w3.y;
  }
  bf16x8s zv;
#pragma unroll
  for (int j = 0; j < 8; ++j) zv[j] = (short)f2bf16bits(acc[j]);
  *(bf16x8s*)&Ztb[((size_t)bi * L_ + row) * M2 + t * 8] = zv;
  if (t == 0) candcntb[bi * L_ + row] = min(mcnt, NCAND);
  if (t < NCAND && t < mcnt) candb[(bi * L_ + row) * NCAND + t] = mlist[t];
}

// ---------------- LDS-tiled transpose (bf16), batched (blockIdx.z = bi)
__global__ __launch_bounds__(256) void transpose_k(const unsigned short* __restrict__ inb,
                                                   unsigned short* __restrict__ outb) {
  __shared__ ushort2 tile[32][33];
  int bi = blockIdx.z;
  const unsigned short* in = inb + (size_t)bi * L_ * M2;
  unsigned short* out = outb + (size_t)bi * M2 * L_;
  int bm2 = blockIdx.x * 32;
  int bh = blockIdx.y * 32;
  int tx = threadIdx.x & 31;
  int ty = threadIdx.x >> 5;
  const ushort2* in2 = (const ushort2*)in;
#pragma unroll
  for (int r = 0; r < 32; r += 8)
    tile[ty + r][tx] = in2[(size_t)(bh + ty + r) * (M2 / 2) + bm2 + tx];
  __syncthreads();
#pragma unroll
  for (int r = 0; r < 32; r += 8) {
    ushort2 v = tile[tx][ty + r];
    int mp = bm2 + ty + r;
    out[(size_t)(2 * mp) * L_ + bh + tx] = v.x;
    out[(size_t)(2 * mp + 1) * L_ + bh + tx] = v.y;
  }
}

// ---------------- exact fp32 rescore, batched (blockIdx.y = bi)
__global__ __launch_bounds__(256) void rescore_k(const float* __restrict__ FP32b,
                                                 const float* __restrict__ U32b,
                                                 const int* __restrict__ candb,
                                                 const int* __restrict__ candcntb,
                                                 float* __restrict__ offout) {
  __shared__ float red[4];
  const int row = blockIdx.x;
  const int bi = blockIdx.y;
  const int t = threadIdx.x;
  const int h = row >> 6, w = row & 63;
  const float* FP32 = FP32b + (size_t)bi * L_ * K1;
  const float* U32 = U32b + (size_t)bi * L_ * K1;
  const int* cand = candb + (size_t)(bi * L_ + row) * NCAND;
  int cnt = candcntb[bi * L_ + row];
  int bestl;
  if (cnt <= 1) {
    bestl = cand[0];
  } else {
    float fv[5];
#pragma unroll
    for (int s = 0; s < 5; ++s) {
      int k = t + s * 256;
      fv[s] = (k < K1) ? FP32[(size_t)row * K1 + k] : 0.f;
    }
    float bestv = -1e30f;
    bestl = 0x7fffffff;
    for (int ci = 0; ci < cnt; ++ci) {
      int l = cand[ci];
      const float* urow = U32 + (size_t)l * K1;
      float dot = 0.f;
#pragma unroll
      for (int s = 0; s < 5; ++s) {
        int k = t + s * 256;
        if (k < K1) dot += fv[s] * urow[k];
      }
#pragma unroll
      for (int o = 32; o; o >>= 1) dot += __shfl_xor(dot, o);
      if ((t & 63) == 0) red[t >> 6] = dot;
      __syncthreads();
      dot = red[0] + red[1] + red[2] + red[3];
      if (dot > bestv || (dot == bestv && l < bestl)) { bestv = dot; bestl = l; }
      __syncthreads();
    }
  }
  if (t == 0) {
    int istar = bestl >> 6, jstar = bestl & 63;
    offout[(size_t)bi * 8192 + row] = (float)(istar - h);
    offout[(size_t)bi * 8192 + L_ + row] = (float)(jstar - w);
  }
}

// ---------------- final gather, 256 threads = 4 u-rows per block
__global__ __launch_bounds__(256) void gather_k(const unsigned short* __restrict__ Z2b,
                                                float* __restrict__ yout) {
  int c = blockIdx.y, bi = blockIdx.z;
  int t = threadIdx.x & 63;
  int u = blockIdx.x * 4 + (threadIdx.x >> 6);
  const unsigned short* Z2 = Z2b + (size_t)bi * M2 * L_;
  int h0 = (u + 1) >> 1, p0 = (u + 1) & 1;
  int h1 = h0 - 1, p1 = p0 + 2;
  float a0 = 0.f, a1 = 0.f;
#pragma unroll
  for (int e = 0; e < 2; ++e) {
    int h = e ? h1 : h0;
    int p = e ? p1 : p0;
    if ((unsigned)h < 64u) {
      const unsigned short* zb = Z2 + (size_t)(c * 16 + p * 4) * L_ + h * 64;
      a0 += bf16bits2f(zb[1 * L_ + t]);
      if (t >= 1) a0 += bf16bits2f(zb[3 * L_ + (t - 1)]);
      if (t < 63) a1 += bf16bits2f(zb[0 * L_ + (t + 1)]);
      a1 += bf16bits2f(zb[2 * L_ + t]);
    }
  }
  size_t ybase = (((size_t)bi * C_ + c) * HH + u) * WW;
  yout[ybase + 2 * t] = a0 * 0.25f;
  yout[ybase + 2 * t + 1] = a1 * 0.25f;
}

extern "C" void kernel_launch(void* const* d_in, const int* in_sizes, int n_in,
                              void* d_out, int out_size, void* d_ws, size_t ws_size,
                              hipStream_t stream) {
  const float* f = (const float*)d_in[0];
  const float* b = (const float*)d_in[1];
  const float* mask = (const float*)d_in[2];
  float* out = (float*)d_out;
  char* ws = (char*)d_ws;

  size_t off = 0;
  float* mm = (float*)(ws + off);          off += 16384;
  int* vlist = (int*)(ws + off);           off += 16384;
  int* vmap = (int*)(ws + off);            off += 16384;
  int* meta = (int*)(ws + off);            off += 16384;
  int* cand = (int*)(ws + off);            off += (size_t)B_ * L_ * NCAND * 4;  // 512KB
  int* candcnt = (int*)(ws + off);         off += 65536;
  bf16* Ucomp = (bf16*)(ws + off);         off += (size_t)B_ * NPAD * K1 * 2;   // 14.2MB
  bf16* FP = (bf16*)(ws + off);            off += (size_t)B_ * L_ * K1 * 2;     // 18.9MB
  float* U32 = (float*)(ws + off);         off += (size_t)B_ * L_ * K1 * 4;     // 37.7MB
  float* FP32 = (float*)(ws + off);        off += (size_t)B_ * L_ * K1 * 4;     // 37.7MB
  uint8_t* BmT8 = (uint8_t*)(ws + off);    off += (size_t)B_ * M2 * L_;         // 16.8MB
  bf16* S = (bf16*)(ws + off);             off += (size_t)B_ * L_ * NPAD * 2;   // 50.3MB
  unsigned short* Zt = (unsigned short*)(ws + off); off += (size_t)B_ * M2 * L_ * 2;  // 33.6MB
  unsigned short* Z2 = (unsigned short*)(ws + off); off += (size_t)B_ * M2 * L_ * 2;  // 33.6MB
  float* yout = out;
  float* offout = out + (size_t)B_ * C_ * HH * WW;

  compact_k<<<1, 256, 0, stream>>>(mask, mm, vlist, vmap, meta);
  prep_all_k<<<PU_BLKS + PF_BLKS + PB_BLKS, 256, 0, stream>>>(f, b, mm, vmap, Ucomp, U32,
                                                              FP, FP32, BmT8);
  gemm_bt<<<1536, 256, 0, stream>>>(FP, Ucomp, S, NPAD, K1);
  softmax_spmv_k<<<dim3(L_, B_), 256, 0, stream>>>(S, vlist, meta, BmT8, Zt, cand, candcnt);
  rescore_k<<<dim3(L_, B_), 256, 0, stream>>>(FP32, U32, cand, candcnt, offout);
  transpose_k<<<dim3(M2 / 64, L_ / 32, B_), 256, 0, stream>>>(Zt, Z2);
  gather_k<<<dim3(32, 128, B_), 256, 0, stream>>>(Z2, yout);
}

// Round 14
// 276.406 us; speedup vs baseline: 1.0158x; 1.0158x over previous
//
#include <hip/hip_runtime.h>
#include <hip/hip_bf16.h>
#include <cstdint>

#define B_  2
#define C_  128
#define HH  128
#define WW  128
#define L_  4096
#define K1  1152
#define M2  2048
#define NPAD 3072
#define NCAND 16
#define MARGIN 0.15f
#define PCUT 1e-3f
#define MAXC 512

typedef __attribute__((ext_vector_type(8))) short bf16x8s;
typedef __attribute__((ext_vector_type(4))) float f32x4;
typedef __attribute__((ext_vector_type(2))) float f32x2;
using bf16 = __hip_bfloat16;

__device__ inline float bf16bits2f(unsigned short s) {
  uint32_t u = ((uint32_t)s) << 16;
  return __builtin_bit_cast(float, u);
}
__device__ inline unsigned short f2bf16bits(float x) {  // RTNE
  uint32_t u = __builtin_bit_cast(uint32_t, x);
  u += 0x7fffu + ((u >> 16) & 1u);
  return (unsigned short)(u >> 16);
}

// OCP e4m3 encode (RTNE)
__device__ inline uint8_t fp8_encode(float v) {
  uint32_t s = (__builtin_bit_cast(uint32_t, v) >> 24) & 0x80u;
  float av = fabsf(v);
  uint32_t byte;
  if (av >= 0.015625f) {
    uint32_t bits = __builtin_bit_cast(uint32_t, av);
    uint32_t mant = bits & 0x7fffffu;
    uint32_t E = bits >> 23;
    uint32_t m3 = (mant + 0x7ffffu + ((mant >> 20) & 1u)) >> 20;
    if (m3 == 8u) { m3 = 0u; E++; }
    int e8 = (int)E - 120;
    if (e8 > 15) { e8 = 15; m3 = 6; }
    byte = ((uint32_t)e8 << 3) | m3;
  } else {
    byte = (uint32_t)(av * 512.f + 0.5f);
  }
  return (uint8_t)(s | byte);
}

#if __has_builtin(__builtin_amdgcn_cvt_pk_f32_fp8)
#define FP8PK(d, hi) __builtin_amdgcn_cvt_pk_f32_fp8((d), (hi))
#else
__device__ inline f32x2 FP8PK(uint32_t d, bool hi) {
  uint32_t b0 = hi ? ((d >> 16) & 0xffu) : (d & 0xffu);
  uint32_t b1 = hi ? (d >> 24) : ((d >> 8) & 0xffu);
  f32x2 r;
  r.x = __builtin_bit_cast(float, ((b0 & 0x80u) << 24) | ((b0 & 0x7fu) << 20)) * 0x1p120f;
  r.y = __builtin_bit_cast(float, ((b1 & 0x80u) << 24) | ((b1 & 0x7fu) << 20)) * 0x1p120f;
  return r;
}
#endif

__device__ inline void gload_lds16(const void* g, void* l) {
  auto gp = reinterpret_cast<const __attribute__((address_space(1))) uint32_t*>(
      reinterpret_cast<uintptr_t>(g));
  auto lp = reinterpret_cast<__attribute__((address_space(3))) uint32_t*>(
      reinterpret_cast<uintptr_t>(l));
  __builtin_amdgcn_global_load_lds(gp, lp, 16, 0, 0);
}

// ---------------- mask validity + valid-column compaction (single block)
__global__ __launch_bounds__(256) void compact_k(const float* __restrict__ mask,
                                                 float* __restrict__ mm,
                                                 int* __restrict__ vlist,
                                                 int* __restrict__ vmap,
                                                 int* __restrict__ meta) {
  __shared__ int wpart[4];
  int t = threadIdx.x;
  int lane = t & 63, wid = t >> 6;
  int loc[16];
  float mmv[16];
  int cnt = 0;
#pragma unroll
  for (int s = 0; s < 16; ++s) {
    int l = t * 16 + s;
    int i = l >> 6, j = l & 63;
    float sum = 0.f;
    for (int p = -1; p <= 1; ++p)
      for (int q = -1; q <= 1; ++q) {
        int y = i + p, x = j + q;
        if ((unsigned)y < 64u && (unsigned)x < 64u)
          sum += mask[(size_t)(8 * y) * 512 + 8 * x];
      }
    mmv[s] = (sum == 0.f) ? 1.f : 0.f;
    mm[l] = mmv[s];
    loc[s] = cnt;
    cnt += (mmv[s] != 0.f) ? 1 : 0;
  }
  int pre = cnt;
#pragma unroll
  for (int o = 1; o < 64; o <<= 1) {
    int u = __shfl_up(pre, o);
    if (lane >= o) pre += u;
  }
  if (lane == 63) wpart[wid] = pre;
  int excl = pre - cnt;
  __syncthreads();
  int base = 0;
  for (int w = 0; w < wid; ++w) base += wpart[w];
  int mybase = base + excl;
#pragma unroll
  for (int s = 0; s < 16; ++s) {
    int l = t * 16 + s;
    if (mmv[s] != 0.f) {
      int pos = mybase + loc[s];
      vlist[pos] = l;
      vmap[l] = pos;
    }
  }
  if (t == 0) {
    int total = wpart[0] + wpart[1] + wpart[2] + wpart[3];
    meta[0] = total;
    meta[1] = L_ - total;
  }
}

// ---------------- Ucomp + U32, batched (blockIdx.y = bi)
__global__ __launch_bounds__(256) void prep_u_k(const float* __restrict__ bsrc,
                                                const float* __restrict__ mm,
                                                const int* __restrict__ vmap,
                                                bf16* __restrict__ Ucomp,
                                                float* __restrict__ U32) {
  __shared__ float red[4];
  int l = blockIdx.x;
  int bi = blockIdx.y;
  if (mm[l] == 0.f) return;
  int pos = vmap[l];
  int i = l >> 6, j = l & 63;
  int t = threadIdx.x;
  float vals[5];
  float ss = 0.f;
#pragma unroll
  for (int s = 0; s < 5; ++s) {
    int k = t + s * 256;
    float v = 0.f;
    if (k < K1) {
      int c = k / 9, r = k - c * 9;
      int p = r / 3, q = r - p * 3;
      int y = i + p - 1, x = j + q - 1;
      if ((unsigned)y < 64u && (unsigned)x < 64u)
        v = bsrc[(((size_t)bi * C_ + c) * HH + 2 * y) * WW + 2 * x];
    }
    vals[s] = v;
    ss += v * v;
  }
#pragma unroll
  for (int o = 32; o; o >>= 1) ss += __shfl_xor(ss, o);
  if ((t & 63) == 0) red[t >> 6] = ss;
  __syncthreads();
  float tot = red[0] + red[1] + red[2] + red[3];
  float den = fmaxf(sqrtf(tot), 1e-4f);
  float inv = 1.f / den;
  size_t cbase = ((size_t)bi * NPAD + pos) * K1;
  size_t obase = ((size_t)bi * L_ + l) * K1;
#pragma unroll
  for (int s = 0; s < 5; ++s) {
    int k = t + s * 256;
    if (k < K1) {
      float u = vals[s] * inv;
      Ucomp[cbase + k] = __float2bfloat16(u);
      U32[obase + k] = u;
    }
  }
}

// ---------------- FP + FP32, batched (blockIdx.y = bi)
__global__ __launch_bounds__(256) void prep_fp_k(const float* __restrict__ f,
                                                 bf16* __restrict__ FP,
                                                 float* __restrict__ FP32) {
  int idx = blockIdx.x * 256 + threadIdx.x;
  int bi = blockIdx.y;
  if (idx >= L_ * K1) return;
  int hw = idx / K1, k = idx - hw * K1;
  int h = hw >> 6, w = hw & 63;
  int c = k / 9, r = k - c * 9;
  int p = r / 3, q = r - p * 3;
  int y = h + p - 1, x = w + q - 1;
  float v = 0.f;
  if ((unsigned)y < 64u && (unsigned)x < 64u)
    v = f[(((size_t)bi * C_ + c) * HH + 2 * y) * WW + 2 * x];
  size_t o = (size_t)bi * L_ * K1 + idx;
  FP[o] = __float2bfloat16(v);
  FP32[o] = v;
}

// ---------------- BmT8, batched (blockIdx.y = bi)
__global__ void prep_bmatT_k(const float* __restrict__ bsrc, uint8_t* __restrict__ BmT8) {
  int idx = blockIdx.x * 256 + threadIdx.x;
  int bi = blockIdx.y;
  if (idx >= M2 * L_) return;
  int l = idx >> 11, m = idx & 2047;
  int c = m >> 4, p = (m >> 2) & 3, q = m & 3;
  int i = l >> 6, j = l & 63;
  int y = 2 * i + p - 1, x = 2 * j + q - 1;
  float v = 0.f;
  if ((unsigned)y < 128u && (unsigned)x < 128u)
    v = bsrc[(((size_t)bi * C_ + c) * HH + y) * WW + x];
  BmT8[(size_t)bi * M2 * L_ + idx] = fp8_encode(v);
}

// ---------------- GEMM (R9 known-good): 128x128, BK=32, 2-buffer,
// global_load_lds staging. Both batches in one dispatch (B select by bm>>12).
__global__ __launch_bounds__(256) void gemm_bt(const bf16* __restrict__ A,
                                               const bf16* __restrict__ Bbase,
                                               bf16* __restrict__ C,
                                               int N, int K) {
  __shared__ __align__(16) bf16 sA[2][128][32];
  __shared__ __align__(16) bf16 sB[2][128][32];
  const int tid = threadIdx.x;
  const int lane = tid & 63;
  const int wid = tid >> 6;
  const int bm = blockIdx.x * 128;
  const int bn = blockIdx.y * 128;
  const bf16* B = Bbase + (size_t)(bm >> 12) * NPAD * K1;
  const int wm = (wid >> 1) * 64;
  const int wn = (wid & 1) * 64;
  const int lrow = lane & 15;
  const int lko = (lane >> 4) * 8;

  f32x4 acc[4][4];
#pragma unroll
  for (int i = 0; i < 4; ++i)
#pragma unroll
    for (int j = 0; j < 4; ++j) acc[i][j] = (f32x4){0.f, 0.f, 0.f, 0.f};

  const int nt = K >> 5;
  const int s0 = tid, s1 = tid + 256;
  const int ar0 = s0 >> 2, ac0 = (s0 & 3) * 8;
  const int ar1 = s1 >> 2, ac1 = (s1 & 3) * 8;

  auto STAGE = [&](int bufi, int t) {
    const int k0 = t * 32;
    gload_lds16(A + (size_t)(bm + ar0) * K + k0 + ac0, &sA[bufi][ar0][ac0]);
    gload_lds16(A + (size_t)(bm + ar1) * K + k0 + ac1, &sA[bufi][ar1][ac1]);
    gload_lds16(B + (size_t)(bn + ar0) * K + k0 + ac0, &sB[bufi][ar0][ac0]);
    gload_lds16(B + (size_t)(bn + ar1) * K + k0 + ac1, &sB[bufi][ar1][ac1]);
  };

  STAGE(0, 0);
  __syncthreads();
  int buf = 0;
  for (int t = 0; t < nt; ++t) {
    if (t + 1 < nt) STAGE(buf ^ 1, t + 1);
    bf16x8s af[4], bfr[4];
#pragma unroll
    for (int fm = 0; fm < 4; ++fm)
      af[fm] = *(const bf16x8s*)&sA[buf][wm + fm * 16 + lrow][lko];
#pragma unroll
    for (int fn = 0; fn < 4; ++fn)
      bfr[fn] = *(const bf16x8s*)&sB[buf][wn + fn * 16 + lrow][lko];
#pragma unroll
    for (int fm = 0; fm < 4; ++fm)
#pragma unroll
      for (int fn = 0; fn < 4; ++fn)
        acc[fm][fn] = __builtin_amdgcn_mfma_f32_16x16x32_bf16(af[fm], bfr[fn], acc[fm][fn], 0, 0, 0);
    __syncthreads();
    buf ^= 1;
  }

  const int crow = (lane >> 4) * 4;
  const int ccol = lane & 15;
#pragma unroll
  for (int fm = 0; fm < 4; ++fm)
#pragma unroll
    for (int fn = 0; fn < 4; ++fn) {
      int r0 = bm + wm + fm * 16 + crow;
      int c0 = bn + wn + fn * 16 + ccol;
#pragma unroll
      for (int r = 0; r < 4; ++r)
        C[(size_t)(r0 + r) * N + c0] = __float2bfloat16(acc[fm][fn][r]);
    }
}

// ---------------- fused softmax + sparse PV, batched (blockIdx.y = bi)
__global__ __launch_bounds__(256) void softmax_spmv_k(const bf16* __restrict__ Sb,
                                                      const int* __restrict__ vlist,
                                                      const int* __restrict__ meta,
                                                      const uint8_t* __restrict__ BmT8b,
                                                      unsigned short* __restrict__ Ztb,
                                                      int* __restrict__ candb,
                                                      int* __restrict__ candcntb) {
  __shared__ float rmax[4];
  __shared__ float rsum[4];
  __shared__ int scnt, mcnt;
  __shared__ int slist[MAXC];
  __shared__ float splist[MAXC];
  __shared__ int mlist[NCAND];
  const int row = blockIdx.x;
  const int bi = blockIdx.y;
  const int t = threadIdx.x;
  const int vcnt = meta[0];
  const int nmask = meta[1];
  const uint8_t* BmT8 = BmT8b + (size_t)bi * M2 * L_;
  if (t == 0) { scnt = 0; mcnt = 0; }
  const bool has = (t < NPAD / 16);
  const int c0 = t * 16;
  float xs[16];
#pragma unroll
  for (int s = 0; s < 16; ++s) xs[s] = -1e30f;
  if (has) {
    const bf16* srow = Sb + ((size_t)bi * L_ + row) * NPAD;
    bf16x8s sv0 = *(const bf16x8s*)&srow[c0];
    bf16x8s sv1 = *(const bf16x8s*)&srow[c0 + 8];
#pragma unroll
    for (int s = 0; s < 8; ++s) {
      xs[s] = bf16bits2f((unsigned short)sv0[s]);
      xs[s + 8] = bf16bits2f((unsigned short)sv1[s]);
    }
  }
  float vmax = -1e30f;
#pragma unroll
  for (int s = 0; s < 16; ++s)
    if (has && c0 + s < vcnt) vmax = fmaxf(vmax, xs[s]);
#pragma unroll
  for (int o = 32; o; o >>= 1) vmax = fmaxf(vmax, __shfl_xor(vmax, o));
  if ((t & 63) == 0) rmax[t >> 6] = vmax;
  __syncthreads();
  vmax = fmaxf(fmaxf(rmax[0], rmax[1]), fmaxf(rmax[2], rmax[3]));
  float gmax = (nmask > 0) ? fmaxf(vmax, 0.f) : vmax;
  float zs = 0.f;
#pragma unroll
  for (int s = 0; s < 16; ++s)
    if (has && c0 + s < vcnt) zs += __expf(10.f * (xs[s] - gmax));
#pragma unroll
  for (int o = 32; o; o >>= 1) zs += __shfl_xor(zs, o);
  if ((t & 63) == 0) rsum[t >> 6] = zs;
  __syncthreads();
  zs = rsum[0] + rsum[1] + rsum[2] + rsum[3] + (float)nmask * __expf(-10.f * gmax);
  float invZ = 1.f / zs;
  float cutx = gmax + __logf(PCUT * zs) * 0.1f;
  if (has) {
#pragma unroll
    for (int s = 0; s < 16; ++s) {
      int c = c0 + s;
      if (c < vcnt) {
        if (xs[s] >= cutx) {
          int pos = atomicAdd(&scnt, 1);
          if (pos < MAXC) {
            slist[pos] = vlist[c];
            splist[pos] = __expf(10.f * (xs[s] - gmax)) * invZ;
          }
        }
        if (xs[s] >= vmax - MARGIN) {
          int pos = atomicAdd(&mcnt, 1);
          if (pos < NCAND) mlist[pos] = vlist[c];
        }
      }
    }
  }
  __syncthreads();
  int nc = min(scnt, MAXC);
  float acc[8] = {0.f, 0.f, 0.f, 0.f, 0.f, 0.f, 0.f, 0.f};
#pragma unroll 4
  for (int ci = 0; ci < nc; ++ci) {
    int l = slist[ci];
    float p = splist[ci];
    const uint32_t* bp = (const uint32_t*)(BmT8 + (size_t)l * M2) + t * 2;
    uint32_t d0 = bp[0], d1 = bp[1];
    f32x2 w0 = FP8PK(d0, false);
    f32x2 w1 = FP8PK(d0, true);
    f32x2 w2 = FP8PK(d1, false);
    f32x2 w3 = FP8PK(d1, true);
    acc[0] += p * w0.x; acc[1] += p * w0.y;
    acc[2] += p * w1.x; acc[3] += p * w1.y;
    acc[4] += p * w2.x; acc[5] += p * w2.y;
    acc[6] += p * w3.x; acc[7] += p * w3.y;
  }
  bf16x8s zv;
#pragma unroll
  for (int j = 0; j < 8; ++j) zv[j] = (short)f2bf16bits(acc[j]);
  *(bf16x8s*)&Ztb[((size_t)bi * L_ + row) * M2 + t * 8] = zv;
  if (t == 0) candcntb[bi * L_ + row] = min(mcnt, NCAND);
  if (t < NCAND && t < mcnt) candb[(bi * L_ + row) * NCAND + t] = mlist[t];
}

// ---------------- LDS-tiled transpose (bf16), batched (blockIdx.z = bi)
__global__ __launch_bounds__(256) void transpose_k(const unsigned short* __restrict__ inb,
                                                   unsigned short* __restrict__ outb) {
  __shared__ ushort2 tile[32][33];
  int bi = blockIdx.z;
  const unsigned short* in = inb + (size_t)bi * L_ * M2;
  unsigned short* out = outb + (size_t)bi * M2 * L_;
  int bm2 = blockIdx.x * 32;
  int bh = blockIdx.y * 32;
  int tx = threadIdx.x & 31;
  int ty = threadIdx.x >> 5;
  const ushort2* in2 = (const ushort2*)in;
#pragma unroll
  for (int r = 0; r < 32; r += 8)
    tile[ty + r][tx] = in2[(size_t)(bh + ty + r) * (M2 / 2) + bm2 + tx];
  __syncthreads();
#pragma unroll
  for (int r = 0; r < 32; r += 8) {
    ushort2 v = tile[tx][ty + r];
    int mp = bm2 + ty + r;
    out[(size_t)(2 * mp) * L_ + bh + tx] = v.x;
    out[(size_t)(2 * mp + 1) * L_ + bh + tx] = v.y;
  }
}

// ---------------- exact fp32 rescore, batched (blockIdx.y = bi)
__global__ __launch_bounds__(256) void rescore_k(const float* __restrict__ FP32b,
                                                 const float* __restrict__ U32b,
                                                 const int* __restrict__ candb,
                                                 const int* __restrict__ candcntb,
                                                 float* __restrict__ offout) {
  __shared__ float red[4];
  const int row = blockIdx.x;
  const int bi = blockIdx.y;
  const int t = threadIdx.x;
  const int h = row >> 6, w = row & 63;
  const float* FP32 = FP32b + (size_t)bi * L_ * K1;
  const float* U32 = U32b + (size_t)bi * L_ * K1;
  const int* cand = candb + (size_t)(bi * L_ + row) * NCAND;
  int cnt = candcntb[bi * L_ + row];
  int bestl;
  if (cnt <= 1) {
    bestl = cand[0];
  } else {
    float fv[5];
#pragma unroll
    for (int s = 0; s < 5; ++s) {
      int k = t + s * 256;
      fv[s] = (k < K1) ? FP32[(size_t)row * K1 + k] : 0.f;
    }
    float bestv = -1e30f;
    bestl = 0x7fffffff;
    for (int ci = 0; ci < cnt; ++ci) {
      int l = cand[ci];
      const float* urow = U32 + (size_t)l * K1;
      float dot = 0.f;
#pragma unroll
      for (int s = 0; s < 5; ++s) {
        int k = t + s * 256;
        if (k < K1) dot += fv[s] * urow[k];
      }
#pragma unroll
      for (int o = 32; o; o >>= 1) dot += __shfl_xor(dot, o);
      if ((t & 63) == 0) red[t >> 6] = dot;
      __syncthreads();
      dot = red[0] + red[1] + red[2] + red[3];
      if (dot > bestv || (dot == bestv && l < bestl)) { bestv = dot; bestl = l; }
      __syncthreads();
    }
  }
  if (t == 0) {
    int istar = bestl >> 6, jstar = bestl & 63;
    offout[(size_t)bi * 8192 + row] = (float)(istar - h);
    offout[(size_t)bi * 8192 + L_ + row] = (float)(jstar - w);
  }
}

// ---------------- final gather, 256 threads = 4 u-rows per block
__global__ __launch_bounds__(256) void gather_k(const unsigned short* __restrict__ Z2b,
                                                float* __restrict__ yout) {
  int c = blockIdx.y, bi = blockIdx.z;
  int t = threadIdx.x & 63;
  int u = blockIdx.x * 4 + (threadIdx.x >> 6);
  const unsigned short* Z2 = Z2b + (size_t)bi * M2 * L_;
  int h0 = (u + 1) >> 1, p0 = (u + 1) & 1;
  int h1 = h0 - 1, p1 = p0 + 2;
  float a0 = 0.f, a1 = 0.f;
#pragma unroll
  for (int e = 0; e < 2; ++e) {
    int h = e ? h1 : h0;
    int p = e ? p1 : p0;
    if ((unsigned)h < 64u) {
      const unsigned short* zb = Z2 + (size_t)(c * 16 + p * 4) * L_ + h * 64;
      a0 += bf16bits2f(zb[1 * L_ + t]);
      if (t >= 1) a0 += bf16bits2f(zb[3 * L_ + (t - 1)]);
      if (t < 63) a1 += bf16bits2f(zb[0 * L_ + (t + 1)]);
      a1 += bf16bits2f(zb[2 * L_ + t]);
    }
  }
  size_t ybase = (((size_t)bi * C_ + c) * HH + u) * WW;
  yout[ybase + 2 * t] = a0 * 0.25f;
  yout[ybase + 2 * t + 1] = a1 * 0.25f;
}

extern "C" void kernel_launch(void* const* d_in, const int* in_sizes, int n_in,
                              void* d_out, int out_size, void* d_ws, size_t ws_size,
                              hipStream_t stream) {
  const float* f = (const float*)d_in[0];
  const float* b = (const float*)d_in[1];
  const float* mask = (const float*)d_in[2];
  float* out = (float*)d_out;
  char* ws = (char*)d_ws;

  size_t off = 0;
  float* mm = (float*)(ws + off);          off += 16384;
  int* vlist = (int*)(ws + off);           off += 16384;
  int* vmap = (int*)(ws + off);            off += 16384;
  int* meta = (int*)(ws + off);            off += 16384;
  int* cand = (int*)(ws + off);            off += (size_t)B_ * L_ * NCAND * 4;  // 512KB
  int* candcnt = (int*)(ws + off);         off += 65536;
  bf16* Ucomp = (bf16*)(ws + off);         off += (size_t)B_ * NPAD * K1 * 2;   // 14.2MB
  bf16* FP = (bf16*)(ws + off);            off += (size_t)B_ * L_ * K1 * 2;     // 18.9MB
  float* U32 = (float*)(ws + off);         off += (size_t)B_ * L_ * K1 * 4;     // 37.7MB
  float* FP32 = (float*)(ws + off);        off += (size_t)B_ * L_ * K1 * 4;     // 37.7MB
  uint8_t* BmT8 = (uint8_t*)(ws + off);    off += (size_t)B_ * M2 * L_;         // 16.8MB
  bf16* S = (bf16*)(ws + off);             off += (size_t)B_ * L_ * NPAD * 2;   // 50.3MB
  unsigned short* Zt = (unsigned short*)(ws + off); off += (size_t)B_ * M2 * L_ * 2;  // 33.6MB
  unsigned short* Z2 = (unsigned short*)(ws + off); off += (size_t)B_ * M2 * L_ * 2;  // 33.6MB
  float* yout = out;
  float* offout = out + (size_t)B_ * C_ * HH * WW;

  compact_k<<<1, 256, 0, stream>>>(mask, mm, vlist, vmap, meta);
  prep_u_k<<<dim3(L_, B_), 256, 0, stream>>>(b, mm, vmap, Ucomp, U32);
  prep_fp_k<<<dim3((L_ * K1 + 255) / 256, B_), 256, 0, stream>>>(f, FP, FP32);
  prep_bmatT_k<<<dim3((M2 * L_ + 255) / 256, B_), 256, 0, stream>>>(b, BmT8);
  gemm_bt<<<dim3(B_ * L_ / 128, NPAD / 128), 256, 0, stream>>>(FP, Ucomp, S, NPAD, K1);
  softmax_spmv_k<<<dim3(L_, B_), 256, 0, stream>>>(S, vlist, meta, BmT8, Zt, cand, candcnt);
  rescore_k<<<dim3(L_, B_), 256, 0, stream>>>(FP32, U32, cand, candcnt, offout);
  transpose_k<<<dim3(M2 / 64, L_ / 32, B_), 256, 0, stream>>>(Zt, Z2);
  gather_k<<<dim3(32, 128, B_), 256, 0, stream>>>(Z2, yout);
}

// Round 15
// 253.192 us; speedup vs baseline: 1.1090x; 1.0917x over previous
//
#include <hip/hip_runtime.h>
#include <hip/hip_bf16.h>
#include <cstdint>

#define B_  2
#define C_  128
#define HH  128
#define WW  128
#define L_  4096
#define K1  1152
#define M2  2048
#define NPAD 2944
#define NCAND 16
#define MARGIN 0.15f
#define PCUT 1e-3f
#define MAXC 512

typedef __attribute__((ext_vector_type(8))) short bf16x8s;
typedef __attribute__((ext_vector_type(4))) float f32x4;
typedef __attribute__((ext_vector_type(2))) float f32x2;
using bf16 = __hip_bfloat16;

__device__ inline float bf16bits2f(unsigned short s) {
  uint32_t u = ((uint32_t)s) << 16;
  return __builtin_bit_cast(float, u);
}
__device__ inline unsigned short f2bf16bits(float x) {  // RTNE
  uint32_t u = __builtin_bit_cast(uint32_t, x);
  u += 0x7fffu + ((u >> 16) & 1u);
  return (unsigned short)(u >> 16);
}

// OCP e4m3 encode (RTNE)
__device__ inline uint8_t fp8_encode(float v) {
  uint32_t s = (__builtin_bit_cast(uint32_t, v) >> 24) & 0x80u;
  float av = fabsf(v);
  uint32_t byte;
  if (av >= 0.015625f) {
    uint32_t bits = __builtin_bit_cast(uint32_t, av);
    uint32_t mant = bits & 0x7fffffu;
    uint32_t E = bits >> 23;
    uint32_t m3 = (mant + 0x7ffffu + ((mant >> 20) & 1u)) >> 20;
    if (m3 == 8u) { m3 = 0u; E++; }
    int e8 = (int)E - 120;
    if (e8 > 15) { e8 = 15; m3 = 6; }
    byte = ((uint32_t)e8 << 3) | m3;
  } else {
    byte = (uint32_t)(av * 512.f + 0.5f);
  }
  return (uint8_t)(s | byte);
}

#if __has_builtin(__builtin_amdgcn_cvt_pk_f32_fp8)
#define FP8PK(d, hi) __builtin_amdgcn_cvt_pk_f32_fp8((d), (hi))
#else
__device__ inline f32x2 FP8PK(uint32_t d, bool hi) {
  uint32_t b0 = hi ? ((d >> 16) & 0xffu) : (d & 0xffu);
  uint32_t b1 = hi ? (d >> 24) : ((d >> 8) & 0xffu);
  f32x2 r;
  r.x = __builtin_bit_cast(float, ((b0 & 0x80u) << 24) | ((b0 & 0x7fu) << 20)) * 0x1p120f;
  r.y = __builtin_bit_cast(float, ((b1 & 0x80u) << 24) | ((b1 & 0x7fu) << 20)) * 0x1p120f;
  return r;
}
#endif

__device__ inline void gload_lds16(const void* g, void* l) {
  auto gp = reinterpret_cast<const __attribute__((address_space(1))) uint32_t*>(
      reinterpret_cast<uintptr_t>(g));
  auto lp = reinterpret_cast<__attribute__((address_space(3))) uint32_t*>(
      reinterpret_cast<uintptr_t>(l));
  __builtin_amdgcn_global_load_lds(gp, lp, 16, 0, 0);
}

// ---------------- mask validity (parallel, 16 blocks)
__global__ void compute_mm_k(const float* __restrict__ mask, float* __restrict__ mm) {
  int l = blockIdx.x * 256 + threadIdx.x;
  if (l >= L_) return;
  int i = l >> 6, j = l & 63;
  float s = 0.f;
  for (int p = -1; p <= 1; ++p)
    for (int q = -1; q <= 1; ++q) {
      int y = i + p, x = j + q;
      if ((unsigned)y < 64u && (unsigned)x < 64u)
        s += mask[(size_t)(8 * y) * 512 + 8 * x];
    }
  mm[l] = (s == 0.f) ? 1.f : 0.f;
}

// ---------------- valid-column compaction (1 block, coalesced mm reads)
__global__ __launch_bounds__(256) void compact_k(const float* __restrict__ mm,
                                                 int* __restrict__ vlist,
                                                 int* __restrict__ vmap,
                                                 int* __restrict__ meta) {
  __shared__ int wpart[4];
  int t = threadIdx.x;
  int lane = t & 63, wid = t >> 6;
  int loc[16];
  int cnt = 0;
#pragma unroll
  for (int s = 0; s < 16; ++s) {
    int l = t * 16 + s;
    loc[s] = cnt;
    cnt += (mm[l] != 0.f) ? 1 : 0;
  }
  int pre = cnt;
#pragma unroll
  for (int o = 1; o < 64; o <<= 1) {
    int u = __shfl_up(pre, o);
    if (lane >= o) pre += u;
  }
  if (lane == 63) wpart[wid] = pre;
  int excl = pre - cnt;
  __syncthreads();
  int base = 0;
  for (int w = 0; w < wid; ++w) base += wpart[w];
  int mybase = base + excl;
#pragma unroll
  for (int s = 0; s < 16; ++s) {
    int l = t * 16 + s;
    if (mm[l] != 0.f) {
      int pos = mybase + loc[s];
      vlist[pos] = l;
      vmap[l] = pos;
    }
  }
  if (t == 0) {
    int total = wpart[0] + wpart[1] + wpart[2] + wpart[3];
    meta[0] = total;
    meta[1] = L_ - total;
  }
}

// ---------------- Ucomp + U32, batched (blockIdx.y = bi)
__global__ __launch_bounds__(256) void prep_u_k(const float* __restrict__ bsrc,
                                                const float* __restrict__ mm,
                                                const int* __restrict__ vmap,
                                                bf16* __restrict__ Ucomp,
                                                float* __restrict__ U32) {
  __shared__ float red[4];
  int l = blockIdx.x;
  int bi = blockIdx.y;
  if (mm[l] == 0.f) return;
  int pos = vmap[l];
  int i = l >> 6, j = l & 63;
  int t = threadIdx.x;
  float vals[5];
  float ss = 0.f;
#pragma unroll
  for (int s = 0; s < 5; ++s) {
    int k = t + s * 256;
    float v = 0.f;
    if (k < K1) {
      int c = k / 9, r = k - c * 9;
      int p = r / 3, q = r - p * 3;
      int y = i + p - 1, x = j + q - 1;
      if ((unsigned)y < 64u && (unsigned)x < 64u)
        v = bsrc[(((size_t)bi * C_ + c) * HH + 2 * y) * WW + 2 * x];
    }
    vals[s] = v;
    ss += v * v;
  }
#pragma unroll
  for (int o = 32; o; o >>= 1) ss += __shfl_xor(ss, o);
  if ((t & 63) == 0) red[t >> 6] = ss;
  __syncthreads();
  float tot = red[0] + red[1] + red[2] + red[3];
  float den = fmaxf(sqrtf(tot), 1e-4f);
  float inv = 1.f / den;
  size_t cbase = ((size_t)bi * NPAD + pos) * K1;
  size_t obase = ((size_t)bi * L_ + l) * K1;
#pragma unroll
  for (int s = 0; s < 5; ++s) {
    int k = t + s * 256;
    if (k < K1) {
      float u = vals[s] * inv;
      Ucomp[cbase + k] = __float2bfloat16(u);
      U32[obase + k] = u;
    }
  }
}

// ---------------- FP + FP32, batched (blockIdx.y = bi)
__global__ __launch_bounds__(256) void prep_fp_k(const float* __restrict__ f,
                                                 bf16* __restrict__ FP,
                                                 float* __restrict__ FP32) {
  int idx = blockIdx.x * 256 + threadIdx.x;
  int bi = blockIdx.y;
  if (idx >= L_ * K1) return;
  int hw = idx / K1, k = idx - hw * K1;
  int h = hw >> 6, w = hw & 63;
  int c = k / 9, r = k - c * 9;
  int p = r / 3, q = r - p * 3;
  int y = h + p - 1, x = w + q - 1;
  float v = 0.f;
  if ((unsigned)y < 64u && (unsigned)x < 64u)
    v = f[(((size_t)bi * C_ + c) * HH + 2 * y) * WW + 2 * x];
  size_t o = (size_t)bi * L_ * K1 + idx;
  FP[o] = __float2bfloat16(v);
  FP32[o] = v;
}

// ---------------- BmT8, batched (blockIdx.y = bi)
__global__ void prep_bmatT_k(const float* __restrict__ bsrc, uint8_t* __restrict__ BmT8) {
  int idx = blockIdx.x * 256 + threadIdx.x;
  int bi = blockIdx.y;
  if (idx >= M2 * L_) return;
  int l = idx >> 11, m = idx & 2047;
  int c = m >> 4, p = (m >> 2) & 3, q = m & 3;
  int i = l >> 6, j = l & 63;
  int y = 2 * i + p - 1, x = 2 * j + q - 1;
  float v = 0.f;
  if ((unsigned)y < 128u && (unsigned)x < 128u)
    v = bsrc[(((size_t)bi * C_ + c) * HH + y) * WW + x];
  BmT8[(size_t)bi * M2 * L_ + idx] = fp8_encode(v);
}

// ---------------- GEMM (known-good): 128x128, BK=32, 2-buffer,
// global_load_lds staging. Both batches in one dispatch (B select by bm>>12).
__global__ __launch_bounds__(256) void gemm_bt(const bf16* __restrict__ A,
                                               const bf16* __restrict__ Bbase,
                                               bf16* __restrict__ C,
                                               int N, int K) {
  __shared__ __align__(16) bf16 sA[2][128][32];
  __shared__ __align__(16) bf16 sB[2][128][32];
  const int tid = threadIdx.x;
  const int lane = tid & 63;
  const int wid = tid >> 6;
  const int bm = blockIdx.x * 128;
  const int bn = blockIdx.y * 128;
  const bf16* B = Bbase + (size_t)(bm >> 12) * NPAD * K1;
  const int wm = (wid >> 1) * 64;
  const int wn = (wid & 1) * 64;
  const int lrow = lane & 15;
  const int lko = (lane >> 4) * 8;

  f32x4 acc[4][4];
#pragma unroll
  for (int i = 0; i < 4; ++i)
#pragma unroll
    for (int j = 0; j < 4; ++j) acc[i][j] = (f32x4){0.f, 0.f, 0.f, 0.f};

  const int nt = K >> 5;
  const int s0 = tid, s1 = tid + 256;
  const int ar0 = s0 >> 2, ac0 = (s0 & 3) * 8;
  const int ar1 = s1 >> 2, ac1 = (s1 & 3) * 8;

  auto STAGE = [&](int bufi, int t) {
    const int k0 = t * 32;
    gload_lds16(A + (size_t)(bm + ar0) * K + k0 + ac0, &sA[bufi][ar0][ac0]);
    gload_lds16(A + (size_t)(bm + ar1) * K + k0 + ac1, &sA[bufi][ar1][ac1]);
    gload_lds16(B + (size_t)(bn + ar0) * K + k0 + ac0, &sB[bufi][ar0][ac0]);
    gload_lds16(B + (size_t)(bn + ar1) * K + k0 + ac1, &sB[bufi][ar1][ac1]);
  };

  STAGE(0, 0);
  __syncthreads();
  int buf = 0;
  for (int t = 0; t < nt; ++t) {
    if (t + 1 < nt) STAGE(buf ^ 1, t + 1);
    bf16x8s af[4], bfr[4];
#pragma unroll
    for (int fm = 0; fm < 4; ++fm)
      af[fm] = *(const bf16x8s*)&sA[buf][wm + fm * 16 + lrow][lko];
#pragma unroll
    for (int fn = 0; fn < 4; ++fn)
      bfr[fn] = *(const bf16x8s*)&sB[buf][wn + fn * 16 + lrow][lko];
#pragma unroll
    for (int fm = 0; fm < 4; ++fm)
#pragma unroll
      for (int fn = 0; fn < 4; ++fn)
        acc[fm][fn] = __builtin_amdgcn_mfma_f32_16x16x32_bf16(af[fm], bfr[fn], acc[fm][fn], 0, 0, 0);
    __syncthreads();
    buf ^= 1;
  }

  const int crow = (lane >> 4) * 4;
  const int ccol = lane & 15;
#pragma unroll
  for (int fm = 0; fm < 4; ++fm)
#pragma unroll
    for (int fn = 0; fn < 4; ++fn) {
      int r0 = bm + wm + fm * 16 + crow;
      int c0 = bn + wn + fn * 16 + ccol;
#pragma unroll
      for (int r = 0; r < 4; ++r)
        C[(size_t)(r0 + r) * N + c0] = __float2bfloat16(acc[fm][fn][r]);
    }
}

// ---------------- fused softmax + sparse PV, batched (blockIdx.y = bi)
__global__ __launch_bounds__(256) void softmax_spmv_k(const bf16* __restrict__ Sb,
                                                      const int* __restrict__ vlist,
                                                      const int* __restrict__ meta,
                                                      const uint8_t* __restrict__ BmT8b,
                                                      unsigned short* __restrict__ Ztb,
                                                      int* __restrict__ candb,
                                                      int* __restrict__ candcntb) {
  __shared__ float rmax[4];
  __shared__ float rsum[4];
  __shared__ int scnt, mcnt;
  __shared__ int slist[MAXC];
  __shared__ float splist[MAXC];
  __shared__ int mlist[NCAND];
  const int row = blockIdx.x;
  const int bi = blockIdx.y;
  const int t = threadIdx.x;
  const int vcnt = meta[0];
  const int nmask = meta[1];
  const uint8_t* BmT8 = BmT8b + (size_t)bi * M2 * L_;
  if (t == 0) { scnt = 0; mcnt = 0; }
  const bool has = (t < NPAD / 16);
  const int c0 = t * 16;
  float xs[16];
#pragma unroll
  for (int s = 0; s < 16; ++s) xs[s] = -1e30f;
  if (has) {
    const bf16* srow = Sb + ((size_t)bi * L_ + row) * NPAD;
    bf16x8s sv0 = *(const bf16x8s*)&srow[c0];
    bf16x8s sv1 = *(const bf16x8s*)&srow[c0 + 8];
#pragma unroll
    for (int s = 0; s < 8; ++s) {
      xs[s] = bf16bits2f((unsigned short)sv0[s]);
      xs[s + 8] = bf16bits2f((unsigned short)sv1[s]);
    }
  }
  float vmax = -1e30f;
#pragma unroll
  for (int s = 0; s < 16; ++s)
    if (has && c0 + s < vcnt) vmax = fmaxf(vmax, xs[s]);
#pragma unroll
  for (int o = 32; o; o >>= 1) vmax = fmaxf(vmax, __shfl_xor(vmax, o));
  if ((t & 63) == 0) rmax[t >> 6] = vmax;
  __syncthreads();
  vmax = fmaxf(fmaxf(rmax[0], rmax[1]), fmaxf(rmax[2], rmax[3]));
  float gmax = (nmask > 0) ? fmaxf(vmax, 0.f) : vmax;
  float zs = 0.f;
#pragma unroll
  for (int s = 0; s < 16; ++s)
    if (has && c0 + s < vcnt) zs += __expf(10.f * (xs[s] - gmax));
#pragma unroll
  for (int o = 32; o; o >>= 1) zs += __shfl_xor(zs, o);
  if ((t & 63) == 0) rsum[t >> 6] = zs;
  __syncthreads();
  zs = rsum[0] + rsum[1] + rsum[2] + rsum[3] + (float)nmask * __expf(-10.f * gmax);
  float invZ = 1.f / zs;
  float cutx = gmax + __logf(PCUT * zs) * 0.1f;
  if (has) {
#pragma unroll
    for (int s = 0; s < 16; ++s) {
      int c = c0 + s;
      if (c < vcnt) {
        if (xs[s] >= cutx) {
          int pos = atomicAdd(&scnt, 1);
          if (pos < MAXC) {
            slist[pos] = vlist[c];
            splist[pos] = __expf(10.f * (xs[s] - gmax)) * invZ;
          }
        }
        if (xs[s] >= vmax - MARGIN) {
          int pos = atomicAdd(&mcnt, 1);
          if (pos < NCAND) mlist[pos] = vlist[c];
        }
      }
    }
  }
  __syncthreads();
  int nc = min(scnt, MAXC);
  float acc[8] = {0.f, 0.f, 0.f, 0.f, 0.f, 0.f, 0.f, 0.f};
#pragma unroll 4
  for (int ci = 0; ci < nc; ++ci) {
    int l = slist[ci];
    float p = splist[ci];
    const uint32_t* bp = (const uint32_t*)(BmT8 + (size_t)l * M2) + t * 2;
    uint32_t d0 = bp[0], d1 = bp[1];
    f32x2 w0 = FP8PK(d0, false);
    f32x2 w1 = FP8PK(d0, true);
    f32x2 w2 = FP8PK(d1, false);
    f32x2 w3 = FP8PK(d1, true);
    acc[0] += p * w0.x; acc[1] += p * w0.y;
    acc[2] += p * w1.x; acc[3] += p * w1.y;
    acc[4] += p * w2.x; acc[5] += p * w2.y;
    acc[6] += p * w3.x; acc[7] += p * w3.y;
  }
  bf16x8s zv;
#pragma unroll
  for (int j = 0; j < 8; ++j) zv[j] = (short)f2bf16bits(acc[j]);
  *(bf16x8s*)&Ztb[((size_t)bi * L_ + row) * M2 + t * 8] = zv;
  if (t == 0) candcntb[bi * L_ + row] = min(mcnt, NCAND);
  if (t < NCAND && t < mcnt) candb[(bi * L_ + row) * NCAND + t] = mlist[t];
}

// ---------------- LDS-tiled transpose (bf16), batched (blockIdx.z = bi)
__global__ __launch_bounds__(256) void transpose_k(const unsigned short* __restrict__ inb,
                                                   unsigned short* __restrict__ outb) {
  __shared__ ushort2 tile[32][33];
  int bi = blockIdx.z;
  const unsigned short* in = inb + (size_t)bi * L_ * M2;
  unsigned short* out = outb + (size_t)bi * M2 * L_;
  int bm2 = blockIdx.x * 32;
  int bh = blockIdx.y * 32;
  int tx = threadIdx.x & 31;
  int ty = threadIdx.x >> 5;
  const ushort2* in2 = (const ushort2*)in;
#pragma unroll
  for (int r = 0; r < 32; r += 8)
    tile[ty + r][tx] = in2[(size_t)(bh + ty + r) * (M2 / 2) + bm2 + tx];
  __syncthreads();
#pragma unroll
  for (int r = 0; r < 32; r += 8) {
    ushort2 v = tile[tx][ty + r];
    int mp = bm2 + ty + r;
    out[(size_t)(2 * mp) * L_ + bh + tx] = v.x;
    out[(size_t)(2 * mp + 1) * L_ + bh + tx] = v.y;
  }
}

// ---------------- exact fp32 rescore, batched (blockIdx.y = bi)
__global__ __launch_bounds__(256) void rescore_k(const float* __restrict__ FP32b,
                                                 const float* __restrict__ U32b,
                                                 const int* __restrict__ candb,
                                                 const int* __restrict__ candcntb,
                                                 float* __restrict__ offout) {
  __shared__ float red[4];
  const int row = blockIdx.x;
  const int bi = blockIdx.y;
  const int t = threadIdx.x;
  const int h = row >> 6, w = row & 63;
  const float* FP32 = FP32b + (size_t)bi * L_ * K1;
  const float* U32 = U32b + (size_t)bi * L_ * K1;
  const int* cand = candb + (size_t)(bi * L_ + row) * NCAND;
  int cnt = candcntb[bi * L_ + row];
  int bestl;
  if (cnt <= 1) {
    bestl = cand[0];
  } else {
    float fv[5];
#pragma unroll
    for (int s = 0; s < 5; ++s) {
      int k = t + s * 256;
      fv[s] = (k < K1) ? FP32[(size_t)row * K1 + k] : 0.f;
    }
    float bestv = -1e30f;
    bestl = 0x7fffffff;
    for (int ci = 0; ci < cnt; ++ci) {
      int l = cand[ci];
      const float* urow = U32 + (size_t)l * K1;
      float dot = 0.f;
#pragma unroll
      for (int s = 0; s < 5; ++s) {
        int k = t + s * 256;
        if (k < K1) dot += fv[s] * urow[k];
      }
#pragma unroll
      for (int o = 32; o; o >>= 1) dot += __shfl_xor(dot, o);
      if ((t & 63) == 0) red[t >> 6] = dot;
      __syncthreads();
      dot = red[0] + red[1] + red[2] + red[3];
      if (dot > bestv || (dot == bestv && l < bestl)) { bestv = dot; bestl = l; }
      __syncthreads();
    }
  }
  if (t == 0) {
    int istar = bestl >> 6, jstar = bestl & 63;
    offout[(size_t)bi * 8192 + row] = (float)(istar - h);
    offout[(size_t)bi * 8192 + L_ + row] = (float)(jstar - w);
  }
}

// ---------------- final gather, 256 threads = 4 u-rows per block
__global__ __launch_bounds__(256) void gather_k(const unsigned short* __restrict__ Z2b,
                                                float* __restrict__ yout) {
  int c = blockIdx.y, bi = blockIdx.z;
  int t = threadIdx.x & 63;
  int u = blockIdx.x * 4 + (threadIdx.x >> 6);
  const unsigned short* Z2 = Z2b + (size_t)bi * M2 * L_;
  int h0 = (u + 1) >> 1, p0 = (u + 1) & 1;
  int h1 = h0 - 1, p1 = p0 + 2;
  float a0 = 0.f, a1 = 0.f;
#pragma unroll
  for (int e = 0; e < 2; ++e) {
    int h = e ? h1 : h0;
    int p = e ? p1 : p0;
    if ((unsigned)h < 64u) {
      const unsigned short* zb = Z2 + (size_t)(c * 16 + p * 4) * L_ + h * 64;
      a0 += bf16bits2f(zb[1 * L_ + t]);
      if (t >= 1) a0 += bf16bits2f(zb[3 * L_ + (t - 1)]);
      if (t < 63) a1 += bf16bits2f(zb[0 * L_ + (t + 1)]);
      a1 += bf16bits2f(zb[2 * L_ + t]);
    }
  }
  size_t ybase = (((size_t)bi * C_ + c) * HH + u) * WW;
  yout[ybase + 2 * t] = a0 * 0.25f;
  yout[ybase + 2 * t + 1] = a1 * 0.25f;
}

extern "C" void kernel_launch(void* const* d_in, const int* in_sizes, int n_in,
                              void* d_out, int out_size, void* d_ws, size_t ws_size,
                              hipStream_t stream) {
  const float* f = (const float*)d_in[0];
  const float* b = (const float*)d_in[1];
  const float* mask = (const float*)d_in[2];
  float* out = (float*)d_out;
  char* ws = (char*)d_ws;

  size_t off = 0;
  float* mm = (float*)(ws + off);          off += 16384;
  int* vlist = (int*)(ws + off);           off += 16384;
  int* vmap = (int*)(ws + off);            off += 16384;
  int* meta = (int*)(ws + off);            off += 16384;
  int* cand = (int*)(ws + off);            off += (size_t)B_ * L_ * NCAND * 4;  // 512KB
  int* candcnt = (int*)(ws + off);         off += 65536;
  bf16* Ucomp = (bf16*)(ws + off);         off += (size_t)B_ * NPAD * K1 * 2;   // 13.6MB
  bf16* FP = (bf16*)(ws + off);            off += (size_t)B_ * L_ * K1 * 2;     // 18.9MB
  float* U32 = (float*)(ws + off);         off += (size_t)B_ * L_ * K1 * 4;     // 37.7MB
  float* FP32 = (float*)(ws + off);        off += (size_t)B_ * L_ * K1 * 4;     // 37.7MB
  uint8_t* BmT8 = (uint8_t*)(ws + off);    off += (size_t)B_ * M2 * L_;         // 16.8MB
  bf16* S = (bf16*)(ws + off);             off += (size_t)B_ * L_ * NPAD * 2;   // 48.2MB
  unsigned short* Zt = (unsigned short*)(ws + off); off += (size_t)B_ * M2 * L_ * 2;  // 33.6MB
  unsigned short* Z2 = (unsigned short*)(ws + off); off += (size_t)B_ * M2 * L_ * 2;  // 33.6MB
  float* yout = out;
  float* offout = out + (size_t)B_ * C_ * HH * WW;

  compute_mm_k<<<16, 256, 0, stream>>>(mask, mm);
  compact_k<<<1, 256, 0, stream>>>(mm, vlist, vmap, meta);
  prep_u_k<<<dim3(L_, B_), 256, 0, stream>>>(b, mm, vmap, Ucomp, U32);
  prep_fp_k<<<dim3((L_ * K1 + 255) / 256, B_), 256, 0, stream>>>(f, FP, FP32);
  prep_bmatT_k<<<dim3((M2 * L_ + 255) / 256, B_), 256, 0, stream>>>(b, BmT8);
  gemm_bt<<<dim3(B_ * L_ / 128, NPAD / 128), 256, 0, stream>>>(FP, Ucomp, S, NPAD, K1);
  softmax_spmv_k<<<dim3(L_, B_), 256, 0, stream>>>(S, vlist, meta, BmT8, Zt, cand, candcnt);
  rescore_k<<<dim3(L_, B_), 256, 0, stream>>>(FP32, U32, cand, candcnt, offout);
  transpose_k<<<dim3(M2 / 64, L_ / 32, B_), 256, 0, stream>>>(Zt, Z2);
  gather_k<<<dim3(32, 128, B_), 256, 0, stream>>>(Z2, yout);
}

// Round 16
// 251.251 us; speedup vs baseline: 1.1175x; 1.0077x over previous
//
#include <hip/hip_runtime.h>
#include <hip/hip_bf16.h>
#include <cstdint>

#define B_  2
#define C_  128
#define HH  128
#define WW  128
#define L_  4096
#define K1  1152
#define M2  2048
#define NPAD 2944
#define NCAND 16
#define MARGIN 0.15f
#define PCUT 1e-3f
#define MAXC 512

typedef __attribute__((ext_vector_type(8))) short bf16x8s;
typedef __attribute__((ext_vector_type(4))) float f32x4;
typedef __attribute__((ext_vector_type(2))) float f32x2;
using bf16 = __hip_bfloat16;

__device__ inline float bf16bits2f(unsigned short s) {
  uint32_t u = ((uint32_t)s) << 16;
  return __builtin_bit_cast(float, u);
}
__device__ inline unsigned short f2bf16bits(float x) {  // RTNE
  uint32_t u = __builtin_bit_cast(uint32_t, x);
  u += 0x7fffu + ((u >> 16) & 1u);
  return (unsigned short)(u >> 16);
}

// OCP e4m3 encode (RTNE)
__device__ inline uint8_t fp8_encode(float v) {
  uint32_t s = (__builtin_bit_cast(uint32_t, v) >> 24) & 0x80u;
  float av = fabsf(v);
  uint32_t byte;
  if (av >= 0.015625f) {
    uint32_t bits = __builtin_bit_cast(uint32_t, av);
    uint32_t mant = bits & 0x7fffffu;
    uint32_t E = bits >> 23;
    uint32_t m3 = (mant + 0x7ffffu + ((mant >> 20) & 1u)) >> 20;
    if (m3 == 8u) { m3 = 0u; E++; }
    int e8 = (int)E - 120;
    if (e8 > 15) { e8 = 15; m3 = 6; }
    byte = ((uint32_t)e8 << 3) | m3;
  } else {
    byte = (uint32_t)(av * 512.f + 0.5f);
  }
  return (uint8_t)(s | byte);
}

#if __has_builtin(__builtin_amdgcn_cvt_pk_f32_fp8)
#define FP8PK(d, hi) __builtin_amdgcn_cvt_pk_f32_fp8((d), (hi))
#else
__device__ inline f32x2 FP8PK(uint32_t d, bool hi) {
  uint32_t b0 = hi ? ((d >> 16) & 0xffu) : (d & 0xffu);
  uint32_t b1 = hi ? (d >> 24) : ((d >> 8) & 0xffu);
  f32x2 r;
  r.x = __builtin_bit_cast(float, ((b0 & 0x80u) << 24) | ((b0 & 0x7fu) << 20)) * 0x1p120f;
  r.y = __builtin_bit_cast(float, ((b1 & 0x80u) << 24) | ((b1 & 0x7fu) << 20)) * 0x1p120f;
  return r;
}
#endif

__device__ inline void gload_lds16(const void* g, void* l) {
  auto gp = reinterpret_cast<const __attribute__((address_space(1))) uint32_t*>(
      reinterpret_cast<uintptr_t>(g));
  auto lp = reinterpret_cast<__attribute__((address_space(3))) uint32_t*>(
      reinterpret_cast<uintptr_t>(l));
  __builtin_amdgcn_global_load_lds(gp, lp, 16, 0, 0);
}

// XCD-chunked row swizzle: consecutive rows land on the SAME XCD's L2.
// 4096 rows = 8 XCDs x 512-row chunks; bijective.
__device__ inline int xcd_row(int bx) { return (bx & 7) * 512 + (bx >> 3); }

// ---------------- mask validity (parallel, 16 blocks)
__global__ void compute_mm_k(const float* __restrict__ mask, float* __restrict__ mm) {
  int l = blockIdx.x * 256 + threadIdx.x;
  if (l >= L_) return;
  int i = l >> 6, j = l & 63;
  float s = 0.f;
  for (int p = -1; p <= 1; ++p)
    for (int q = -1; q <= 1; ++q) {
      int y = i + p, x = j + q;
      if ((unsigned)y < 64u && (unsigned)x < 64u)
        s += mask[(size_t)(8 * y) * 512 + 8 * x];
    }
  mm[l] = (s == 0.f) ? 1.f : 0.f;
}

// ---------------- valid-column compaction (1 block, coalesced mm reads)
__global__ __launch_bounds__(256) void compact_k(const float* __restrict__ mm,
                                                 int* __restrict__ vlist,
                                                 int* __restrict__ vmap,
                                                 int* __restrict__ meta) {
  __shared__ int wpart[4];
  int t = threadIdx.x;
  int lane = t & 63, wid = t >> 6;
  int loc[16];
  int cnt = 0;
#pragma unroll
  for (int s = 0; s < 16; ++s) {
    int l = t * 16 + s;
    loc[s] = cnt;
    cnt += (mm[l] != 0.f) ? 1 : 0;
  }
  int pre = cnt;
#pragma unroll
  for (int o = 1; o < 64; o <<= 1) {
    int u = __shfl_up(pre, o);
    if (lane >= o) pre += u;
  }
  if (lane == 63) wpart[wid] = pre;
  int excl = pre - cnt;
  __syncthreads();
  int base = 0;
  for (int w = 0; w < wid; ++w) base += wpart[w];
  int mybase = base + excl;
#pragma unroll
  for (int s = 0; s < 16; ++s) {
    int l = t * 16 + s;
    if (mm[l] != 0.f) {
      int pos = mybase + loc[s];
      vlist[pos] = l;
      vmap[l] = pos;
    }
  }
  if (t == 0) {
    int total = wpart[0] + wpart[1] + wpart[2] + wpart[3];
    meta[0] = total;
    meta[1] = L_ - total;
  }
}

// ---------------- Ucomp + U32, batched (blockIdx.y = bi)
__global__ __launch_bounds__(256) void prep_u_k(const float* __restrict__ bsrc,
                                                const float* __restrict__ mm,
                                                const int* __restrict__ vmap,
                                                bf16* __restrict__ Ucomp,
                                                float* __restrict__ U32) {
  __shared__ float red[4];
  int l = blockIdx.x;
  int bi = blockIdx.y;
  if (mm[l] == 0.f) return;
  int pos = vmap[l];
  int i = l >> 6, j = l & 63;
  int t = threadIdx.x;
  float vals[5];
  float ss = 0.f;
#pragma unroll
  for (int s = 0; s < 5; ++s) {
    int k = t + s * 256;
    float v = 0.f;
    if (k < K1) {
      int c = k / 9, r = k - c * 9;
      int p = r / 3, q = r - p * 3;
      int y = i + p - 1, x = j + q - 1;
      if ((unsigned)y < 64u && (unsigned)x < 64u)
        v = bsrc[(((size_t)bi * C_ + c) * HH + 2 * y) * WW + 2 * x];
    }
    vals[s] = v;
    ss += v * v;
  }
#pragma unroll
  for (int o = 32; o; o >>= 1) ss += __shfl_xor(ss, o);
  if ((t & 63) == 0) red[t >> 6] = ss;
  __syncthreads();
  float tot = red[0] + red[1] + red[2] + red[3];
  float den = fmaxf(sqrtf(tot), 1e-4f);
  float inv = 1.f / den;
  size_t cbase = ((size_t)bi * NPAD + pos) * K1;
  size_t obase = ((size_t)bi * L_ + l) * K1;
#pragma unroll
  for (int s = 0; s < 5; ++s) {
    int k = t + s * 256;
    if (k < K1) {
      float u = vals[s] * inv;
      Ucomp[cbase + k] = __float2bfloat16(u);
      U32[obase + k] = u;
    }
  }
}

// ---------------- FP + FP32, batched (blockIdx.y = bi)
__global__ __launch_bounds__(256) void prep_fp_k(const float* __restrict__ f,
                                                 bf16* __restrict__ FP,
                                                 float* __restrict__ FP32) {
  int idx = blockIdx.x * 256 + threadIdx.x;
  int bi = blockIdx.y;
  if (idx >= L_ * K1) return;
  int hw = idx / K1, k = idx - hw * K1;
  int h = hw >> 6, w = hw & 63;
  int c = k / 9, r = k - c * 9;
  int p = r / 3, q = r - p * 3;
  int y = h + p - 1, x = w + q - 1;
  float v = 0.f;
  if ((unsigned)y < 64u && (unsigned)x < 64u)
    v = f[(((size_t)bi * C_ + c) * HH + 2 * y) * WW + 2 * x];
  size_t o = (size_t)bi * L_ * K1 + idx;
  FP[o] = __float2bfloat16(v);
  FP32[o] = v;
}

// ---------------- BmT8, batched (blockIdx.y = bi)
__global__ void prep_bmatT_k(const float* __restrict__ bsrc, uint8_t* __restrict__ BmT8) {
  int idx = blockIdx.x * 256 + threadIdx.x;
  int bi = blockIdx.y;
  if (idx >= M2 * L_) return;
  int l = idx >> 11, m = idx & 2047;
  int c = m >> 4, p = (m >> 2) & 3, q = m & 3;
  int i = l >> 6, j = l & 63;
  int y = 2 * i + p - 1, x = 2 * j + q - 1;
  float v = 0.f;
  if ((unsigned)y < 128u && (unsigned)x < 128u)
    v = bsrc[(((size_t)bi * C_ + c) * HH + y) * WW + x];
  BmT8[(size_t)bi * M2 * L_ + idx] = fp8_encode(v);
}

// ---------------- GEMM (known-good): 128x128, BK=32, 2-buffer,
// global_load_lds staging. Both batches in one dispatch (B select by bm>>12).
__global__ __launch_bounds__(256) void gemm_bt(const bf16* __restrict__ A,
                                               const bf16* __restrict__ Bbase,
                                               bf16* __restrict__ C,
                                               int N, int K) {
  __shared__ __align__(16) bf16 sA[2][128][32];
  __shared__ __align__(16) bf16 sB[2][128][32];
  const int tid = threadIdx.x;
  const int lane = tid & 63;
  const int wid = tid >> 6;
  const int bm = blockIdx.x * 128;
  const int bn = blockIdx.y * 128;
  const bf16* B = Bbase + (size_t)(bm >> 12) * NPAD * K1;
  const int wm = (wid >> 1) * 64;
  const int wn = (wid & 1) * 64;
  const int lrow = lane & 15;
  const int lko = (lane >> 4) * 8;

  f32x4 acc[4][4];
#pragma unroll
  for (int i = 0; i < 4; ++i)
#pragma unroll
    for (int j = 0; j < 4; ++j) acc[i][j] = (f32x4){0.f, 0.f, 0.f, 0.f};

  const int nt = K >> 5;
  const int s0 = tid, s1 = tid + 256;
  const int ar0 = s0 >> 2, ac0 = (s0 & 3) * 8;
  const int ar1 = s1 >> 2, ac1 = (s1 & 3) * 8;

  auto STAGE = [&](int bufi, int t) {
    const int k0 = t * 32;
    gload_lds16(A + (size_t)(bm + ar0) * K + k0 + ac0, &sA[bufi][ar0][ac0]);
    gload_lds16(A + (size_t)(bm + ar1) * K + k0 + ac1, &sA[bufi][ar1][ac1]);
    gload_lds16(B + (size_t)(bn + ar0) * K + k0 + ac0, &sB[bufi][ar0][ac0]);
    gload_lds16(B + (size_t)(bn + ar1) * K + k0 + ac1, &sB[bufi][ar1][ac1]);
  };

  STAGE(0, 0);
  __syncthreads();
  int buf = 0;
  for (int t = 0; t < nt; ++t) {
    if (t + 1 < nt) STAGE(buf ^ 1, t + 1);
    bf16x8s af[4], bfr[4];
#pragma unroll
    for (int fm = 0; fm < 4; ++fm)
      af[fm] = *(const bf16x8s*)&sA[buf][wm + fm * 16 + lrow][lko];
#pragma unroll
    for (int fn = 0; fn < 4; ++fn)
      bfr[fn] = *(const bf16x8s*)&sB[buf][wn + fn * 16 + lrow][lko];
#pragma unroll
    for (int fm = 0; fm < 4; ++fm)
#pragma unroll
      for (int fn = 0; fn < 4; ++fn)
        acc[fm][fn] = __builtin_amdgcn_mfma_f32_16x16x32_bf16(af[fm], bfr[fn], acc[fm][fn], 0, 0, 0);
    __syncthreads();
    buf ^= 1;
  }

  const int crow = (lane >> 4) * 4;
  const int ccol = lane & 15;
#pragma unroll
  for (int fm = 0; fm < 4; ++fm)
#pragma unroll
    for (int fn = 0; fn < 4; ++fn) {
      int r0 = bm + wm + fm * 16 + crow;
      int c0 = bn + wn + fn * 16 + ccol;
#pragma unroll
      for (int r = 0; r < 4; ++r)
        C[(size_t)(r0 + r) * N + c0] = __float2bfloat16(acc[fm][fn][r]);
    }
}

// ---------------- fused softmax + sparse PV, batched (blockIdx.y = bi)
// Row mapping XCD-chunked: adjacent rows (correlated candidate sets) share an XCD L2.
__global__ __launch_bounds__(256) void softmax_spmv_k(const bf16* __restrict__ Sb,
                                                      const int* __restrict__ vlist,
                                                      const int* __restrict__ meta,
                                                      const uint8_t* __restrict__ BmT8b,
                                                      unsigned short* __restrict__ Ztb,
                                                      int* __restrict__ candb,
                                                      int* __restrict__ candcntb) {
  __shared__ float rmax[4];
  __shared__ float rsum[4];
  __shared__ int scnt, mcnt;
  __shared__ int slist[MAXC];
  __shared__ float splist[MAXC];
  __shared__ int mlist[NCAND];
  const int row = xcd_row(blockIdx.x);
  const int bi = blockIdx.y;
  const int t = threadIdx.x;
  const int vcnt = meta[0];
  const int nmask = meta[1];
  const uint8_t* BmT8 = BmT8b + (size_t)bi * M2 * L_;
  if (t == 0) { scnt = 0; mcnt = 0; }
  const bool has = (t < NPAD / 16);
  const int c0 = t * 16;
  float xs[16];
#pragma unroll
  for (int s = 0; s < 16; ++s) xs[s] = -1e30f;
  if (has) {
    const bf16* srow = Sb + ((size_t)bi * L_ + row) * NPAD;
    bf16x8s sv0 = *(const bf16x8s*)&srow[c0];
    bf16x8s sv1 = *(const bf16x8s*)&srow[c0 + 8];
#pragma unroll
    for (int s = 0; s < 8; ++s) {
      xs[s] = bf16bits2f((unsigned short)sv0[s]);
      xs[s + 8] = bf16bits2f((unsigned short)sv1[s]);
    }
  }
  float vmax = -1e30f;
#pragma unroll
  for (int s = 0; s < 16; ++s)
    if (has && c0 + s < vcnt) vmax = fmaxf(vmax, xs[s]);
#pragma unroll
  for (int o = 32; o; o >>= 1) vmax = fmaxf(vmax, __shfl_xor(vmax, o));
  if ((t & 63) == 0) rmax[t >> 6] = vmax;
  __syncthreads();
  vmax = fmaxf(fmaxf(rmax[0], rmax[1]), fmaxf(rmax[2], rmax[3]));
  float gmax = (nmask > 0) ? fmaxf(vmax, 0.f) : vmax;
  float zs = 0.f;
#pragma unroll
  for (int s = 0; s < 16; ++s)
    if (has && c0 + s < vcnt) zs += __expf(10.f * (xs[s] - gmax));
#pragma unroll
  for (int o = 32; o; o >>= 1) zs += __shfl_xor(zs, o);
  if ((t & 63) == 0) rsum[t >> 6] = zs;
  __syncthreads();
  zs = rsum[0] + rsum[1] + rsum[2] + rsum[3] + (float)nmask * __expf(-10.f * gmax);
  float invZ = 1.f / zs;
  float cutx = gmax + __logf(PCUT * zs) * 0.1f;
  if (has) {
#pragma unroll
    for (int s = 0; s < 16; ++s) {
      int c = c0 + s;
      if (c < vcnt) {
        if (xs[s] >= cutx) {
          int pos = atomicAdd(&scnt, 1);
          if (pos < MAXC) {
            slist[pos] = vlist[c];
            splist[pos] = __expf(10.f * (xs[s] - gmax)) * invZ;
          }
        }
        if (xs[s] >= vmax - MARGIN) {
          int pos = atomicAdd(&mcnt, 1);
          if (pos < NCAND) mlist[pos] = vlist[c];
        }
      }
    }
  }
  __syncthreads();
  int nc = min(scnt, MAXC);
  float acc[8] = {0.f, 0.f, 0.f, 0.f, 0.f, 0.f, 0.f, 0.f};
#pragma unroll 4
  for (int ci = 0; ci < nc; ++ci) {
    int l = slist[ci];
    float p = splist[ci];
    const uint32_t* bp = (const uint32_t*)(BmT8 + (size_t)l * M2) + t * 2;
    uint32_t d0 = bp[0], d1 = bp[1];
    f32x2 w0 = FP8PK(d0, false);
    f32x2 w1 = FP8PK(d0, true);
    f32x2 w2 = FP8PK(d1, false);
    f32x2 w3 = FP8PK(d1, true);
    acc[0] += p * w0.x; acc[1] += p * w0.y;
    acc[2] += p * w1.x; acc[3] += p * w1.y;
    acc[4] += p * w2.x; acc[5] += p * w2.y;
    acc[6] += p * w3.x; acc[7] += p * w3.y;
  }
  bf16x8s zv;
#pragma unroll
  for (int j = 0; j < 8; ++j) zv[j] = (short)f2bf16bits(acc[j]);
  *(bf16x8s*)&Ztb[((size_t)bi * L_ + row) * M2 + t * 8] = zv;
  if (t == 0) candcntb[bi * L_ + row] = min(mcnt, NCAND);
  if (t < NCAND && t < mcnt) candb[(bi * L_ + row) * NCAND + t] = mlist[t];
}

// ---------------- LDS-tiled transpose (bf16), batched (blockIdx.z = bi)
__global__ __launch_bounds__(256) void transpose_k(const unsigned short* __restrict__ inb,
                                                   unsigned short* __restrict__ outb) {
  __shared__ ushort2 tile[32][33];
  int bi = blockIdx.z;
  const unsigned short* in = inb + (size_t)bi * L_ * M2;
  unsigned short* out = outb + (size_t)bi * M2 * L_;
  int bm2 = blockIdx.x * 32;
  int bh = blockIdx.y * 32;
  int tx = threadIdx.x & 31;
  int ty = threadIdx.x >> 5;
  const ushort2* in2 = (const ushort2*)in;
#pragma unroll
  for (int r = 0; r < 32; r += 8)
    tile[ty + r][tx] = in2[(size_t)(bh + ty + r) * (M2 / 2) + bm2 + tx];
  __syncthreads();
#pragma unroll
  for (int r = 0; r < 32; r += 8) {
    ushort2 v = tile[tx][ty + r];
    int mp = bm2 + ty + r;
    out[(size_t)(2 * mp) * L_ + bh + tx] = v.x;
    out[(size_t)(2 * mp + 1) * L_ + bh + tx] = v.y;
  }
}

// ---------------- exact fp32 rescore, batched (blockIdx.y = bi), XCD-chunked rows
__global__ __launch_bounds__(256) void rescore_k(const float* __restrict__ FP32b,
                                                 const float* __restrict__ U32b,
                                                 const int* __restrict__ candb,
                                                 const int* __restrict__ candcntb,
                                                 float* __restrict__ offout) {
  __shared__ float red[4];
  const int row = xcd_row(blockIdx.x);
  const int bi = blockIdx.y;
  const int t = threadIdx.x;
  const int h = row >> 6, w = row & 63;
  const float* FP32 = FP32b + (size_t)bi * L_ * K1;
  const float* U32 = U32b + (size_t)bi * L_ * K1;
  const int* cand = candb + (size_t)(bi * L_ + row) * NCAND;
  int cnt = candcntb[bi * L_ + row];
  int bestl;
  if (cnt <= 1) {
    bestl = cand[0];
  } else {
    float fv[5];
#pragma unroll
    for (int s = 0; s < 5; ++s) {
      int k = t + s * 256;
      fv[s] = (k < K1) ? FP32[(size_t)row * K1 + k] : 0.f;
    }
    float bestv = -1e30f;
    bestl = 0x7fffffff;
    for (int ci = 0; ci < cnt; ++ci) {
      int l = cand[ci];
      const float* urow = U32 + (size_t)l * K1;
      float dot = 0.f;
#pragma unroll
      for (int s = 0; s < 5; ++s) {
        int k = t + s * 256;
        if (k < K1) dot += fv[s] * urow[k];
      }
#pragma unroll
      for (int o = 32; o; o >>= 1) dot += __shfl_xor(dot, o);
      if ((t & 63) == 0) red[t >> 6] = dot;
      __syncthreads();
      dot = red[0] + red[1] + red[2] + red[3];
      if (dot > bestv || (dot == bestv && l < bestl)) { bestv = dot; bestl = l; }
      __syncthreads();
    }
  }
  if (t == 0) {
    int istar = bestl >> 6, jstar = bestl & 63;
    offout[(size_t)bi * 8192 + row] = (float)(istar - h);
    offout[(size_t)bi * 8192 + L_ + row] = (float)(jstar - w);
  }
}

// ---------------- final gather, 256 threads = 4 u-rows per block
__global__ __launch_bounds__(256) void gather_k(const unsigned short* __restrict__ Z2b,
                                                float* __restrict__ yout) {
  int c = blockIdx.y, bi = blockIdx.z;
  int t = threadIdx.x & 63;
  int u = blockIdx.x * 4 + (threadIdx.x >> 6);
  const unsigned short* Z2 = Z2b + (size_t)bi * M2 * L_;
  int h0 = (u + 1) >> 1, p0 = (u + 1) & 1;
  int h1 = h0 - 1, p1 = p0 + 2;
  float a0 = 0.f, a1 = 0.f;
#pragma unroll
  for (int e = 0; e < 2; ++e) {
    int h = e ? h1 : h0;
    int p = e ? p1 : p0;
    if ((unsigned)h < 64u) {
      const unsigned short* zb = Z2 + (size_t)(c * 16 + p * 4) * L_ + h * 64;
      a0 += bf16bits2f(zb[1 * L_ + t]);
      if (t >= 1) a0 += bf16bits2f(zb[3 * L_ + (t - 1)]);
      if (t < 63) a1 += bf16bits2f(zb[0 * L_ + (t + 1)]);
      a1 += bf16bits2f(zb[2 * L_ + t]);
    }
  }
  size_t ybase = (((size_t)bi * C_ + c) * HH + u) * WW;
  yout[ybase + 2 * t] = a0 * 0.25f;
  yout[ybase + 2 * t + 1] = a1 * 0.25f;
}

extern "C" void kernel_launch(void* const* d_in, const int* in_sizes, int n_in,
                              void* d_out, int out_size, void* d_ws, size_t ws_size,
                              hipStream_t stream) {
  const float* f = (const float*)d_in[0];
  const float* b = (const float*)d_in[1];
  const float* mask = (const float*)d_in[2];
  float* out = (float*)d_out;
  char* ws = (char*)d_ws;

  size_t off = 0;
  float* mm = (float*)(ws + off);          off += 16384;
  int* vlist = (int*)(ws + off);           off += 16384;
  int* vmap = (int*)(ws + off);            off += 16384;
  int* meta = (int*)(ws + off);            off += 16384;
  int* cand = (int*)(ws + off);            off += (size_t)B_ * L_ * NCAND * 4;  // 512KB
  int* candcnt = (int*)(ws + off);         off += 65536;
  bf16* Ucomp = (bf16*)(ws + off);         off += (size_t)B_ * NPAD * K1 * 2;   // 13.6MB
  bf16* FP = (bf16*)(ws + off);            off += (size_t)B_ * L_ * K1 * 2;     // 18.9MB
  float* U32 = (float*)(ws + off);         off += (size_t)B_ * L_ * K1 * 4;     // 37.7MB
  float* FP32 = (float*)(ws + off);        off += (size_t)B_ * L_ * K1 * 4;     // 37.7MB
  uint8_t* BmT8 = (uint8_t*)(ws + off);    off += (size_t)B_ * M2 * L_;         // 16.8MB
  bf16* S = (bf16*)(ws + off);             off += (size_t)B_ * L_ * NPAD * 2;   // 48.2MB
  unsigned short* Zt = (unsigned short*)(ws + off); off += (size_t)B_ * M2 * L_ * 2;  // 33.6MB
  unsigned short* Z2 = (unsigned short*)(ws + off); off += (size_t)B_ * M2 * L_ * 2;  // 33.6MB
  float* yout = out;
  float* offout = out + (size_t)B_ * C_ * HH * WW;

  compute_mm_k<<<16, 256, 0, stream>>>(mask, mm);
  compact_k<<<1, 256, 0, stream>>>(mm, vlist, vmap, meta);
  prep_u_k<<<dim3(L_, B_), 256, 0, stream>>>(b, mm, vmap, Ucomp, U32);
  prep_fp_k<<<dim3((L_ * K1 + 255) / 256, B_), 256, 0, stream>>>(f, FP, FP32);
  prep_bmatT_k<<<dim3((M2 * L_ + 255) / 256, B_), 256, 0, stream>>>(b, BmT8);
  gemm_bt<<<dim3(B_ * L_ / 128, NPAD / 128), 256, 0, stream>>>(FP, Ucomp, S, NPAD, K1);
  softmax_spmv_k<<<dim3(L_, B_), 256, 0, stream>>>(S, vlist, meta, BmT8, Zt, cand, candcnt);
  rescore_k<<<dim3(L_, B_), 256, 0, stream>>>(FP32, U32, cand, candcnt, offout);
  transpose_k<<<dim3(M2 / 64, L_ / 32, B_), 256, 0, stream>>>(Zt, Z2);
  gather_k<<<dim3(32, 128, B_), 256, 0, stream>>>(Z2, yout);
}